// Round 8
// baseline (230.933 us; speedup 1.0000x reference)
//
#include <hip/hip_runtime.h>
#include <hip/hip_bf16.h>

#define N_NODES 50000
#define N_EDGES 400000
#define DIM     128
#define NREL    8
#define NBASES  4
#define KCAT    1152            // 8*128 relation slices + 128 self-loop
#define TN      32              // nodes per mega-block

typedef __hip_bfloat16 bf16;

typedef __bf16 bf16x8 __attribute__((ext_vector_type(8)));
typedef float  f32x4  __attribute__((ext_vector_type(4)));

union frag_u { bf16x8 v; bf16 e[8]; };
union pack4_u { unsigned long long ll; bf16 b[4]; };

// ---- workspace layout (bytes) ----
// hb16  bf16 [N][D]        : 12,800,000
// recs  uint2 [E]          :  3,200,000  (key=(src<<3)|et, bits(norm))
// base  int [N+1] pad      :    200,064
// cur   int [N]   pad      :    200,064
// WcatT bf16 [D][KCAT]     :    294,912  (WcatT[o][r*128+i]=W_r[i][o]; [o][1024+i]=loop_w[i][o])
// fwTb  bf16 [D][D]        :     32,768  (fwTb[o][i] = ffn_w[o][i])
#define HB16_OFF  0LL
#define RECS_OFF  12800000LL
#define BASE_OFF  16000000LL
#define CUR_OFF   16200064LL
#define WCAT_OFF  16400128LL
#define FWT_OFF   16695040LL
#define WS_NEEDED 16727808LL

__device__ __forceinline__ int swzb(int row) { return (row & 15) << 4; }  // 256B subtile
__device__ __forceinline__ int swzy(int row) { return (row & 31) << 4; }  // 512B rows

// ---------------------------------------------------------------------------
// K_prep: hb16 = bf16(h); WcatT (stacked relation+loop weights, transposed);
//         fwTb; in-degree histogram. cur pre-zeroed by memsetAsync.
__global__ __launch_bounds__(256)
void k_prep(const float* __restrict__ h, const float* __restrict__ V,
            const float* __restrict__ wc,
            const float* __restrict__ loop_w, const float* __restrict__ ffn_w,
            const int* __restrict__ dst,
            bf16* __restrict__ hb, bf16* __restrict__ WcatT,
            bf16* __restrict__ fwTb, int* __restrict__ cur) {
    int p = blockIdx.x * 256 + threadIdx.x;
    if (p < N_NODES * DIM / 8) {
        const float* s = h + (long long)p * 8;
        f32x4 lo = *(const f32x4*)s, hi = *(const f32x4*)(s + 4);
        frag_u o;
#pragma unroll
        for (int j = 0; j < 4; ++j) {
            o.e[j]     = __float2bfloat16(lo[j]);
            o.e[4 + j] = __float2bfloat16(hi[j]);
        }
        *(bf16x8*)(hb + (long long)p * 8) = o.v;
    }
    if (p < N_EDGES) atomicAdd(&cur[dst[p]], 1);
    if (p < DIM * KCAT) {
        int o = p / KCAT, k = p % KCAT;
        float val;
        if (k < 1024) {
            int r = k >> 7, i = k & 127;
            val = 0.f;
#pragma unroll
            for (int b = 0; b < NBASES; ++b)
                val += wc[r * NBASES + b] * V[(b << 14) + i * DIM + o];
        } else {
            int i = k - 1024;
            val = loop_w[i * DIM + o];
        }
        WcatT[p] = __float2bfloat16(val);
    }
    if (p < DIM * DIM) {
        fwTb[p] = __float2bfloat16(ffn_w[p]);   // ffn_w[o][i]
    }
}

// ---------------------------------------------------------------------------
// K_scan: exclusive prefix sum of cur -> base; cur <- base. 1 block.
#define SCAN_V 13
__global__ __launch_bounds__(1024)
void k_scan(int* __restrict__ cur, int* __restrict__ base) {
    __shared__ int wsum[16];
    const int t = threadIdx.x, lane = t & 63, wv = t >> 6;
    const int i0 = t * (SCAN_V * 4);
    int4 v[SCAN_V];
#pragma unroll
    for (int i = 0; i < SCAN_V; ++i) {
        int idx = i0 + i * 4;
        if (idx + 3 < N_NODES) v[i] = *(const int4*)(cur + idx);
        else {
            v[i].x = (idx + 0 < N_NODES) ? cur[idx + 0] : 0;
            v[i].y = (idx + 1 < N_NODES) ? cur[idx + 1] : 0;
            v[i].z = (idx + 2 < N_NODES) ? cur[idx + 2] : 0;
            v[i].w = (idx + 3 < N_NODES) ? cur[idx + 3] : 0;
        }
    }
    int s = 0;
#pragma unroll
    for (int i = 0; i < SCAN_V; ++i) s += v[i].x + v[i].y + v[i].z + v[i].w;
    int inc = s;
#pragma unroll
    for (int m = 1; m < 64; m <<= 1) {
        int u = __shfl_up(inc, m);
        if (lane >= m) inc += u;
    }
    if (lane == 63) wsum[wv] = inc;
    __syncthreads();
    if (t < 16) {
        int w = wsum[t];
        int winc = w;
#pragma unroll
        for (int m = 1; m < 16; m <<= 1) {
            int u = __shfl_up(winc, m);
            if (t >= m) winc += u;
        }
        wsum[t] = winc - w;
    }
    __syncthreads();
    int run = wsum[wv] + (inc - s);
#pragma unroll
    for (int i = 0; i < SCAN_V; ++i) {
        int idx = i0 + i * 4;
        if (idx + 3 < N_NODES) {
            int4 o;
            o.x = run; o.y = o.x + v[i].x; o.z = o.y + v[i].y; o.w = o.z + v[i].z;
            run = o.w + v[i].w;
            *(int4*)(base + idx) = o;
            *(int4*)(cur + idx) = o;
        } else {
            if (idx + 0 < N_NODES) { base[idx+0] = run; cur[idx+0] = run; run += v[i].x; }
            if (idx + 1 < N_NODES) { base[idx+1] = run; cur[idx+1] = run; run += v[i].y; }
            if (idx + 2 < N_NODES) { base[idx+2] = run; cur[idx+2] = run; run += v[i].z; }
            if (idx + 3 < N_NODES) { base[idx+3] = run; cur[idx+3] = run; run += v[i].w; }
        }
    }
    if (t == 1023) base[N_NODES] = run;
}

// ---------------------------------------------------------------------------
// K_scatter: bucket edges by dst; recs = {(src<<3)|et, bits(norm)}.
__global__ __launch_bounds__(256)
void k_scatter(const int* __restrict__ src, const int* __restrict__ dst,
               const int* __restrict__ et, const float* __restrict__ norm,
               int* __restrict__ cur, uint2* __restrict__ recs) {
    int e = blockIdx.x * 256 + threadIdx.x;
    if (e >= N_EDGES) return;
    int d = dst[e];
    int pos = atomicAdd(&cur[d], 1);
    uint2 rc;
    rc.x = ((unsigned)src[e] << 3) | (unsigned)et[e];
    rc.y = __float_as_uint(norm[e]);
    recs[pos] = rc;
}

// ---------------------------------------------------------------------------
// K_mega: per 32-node block (512 thr, 8 waves):
//  P1 gather: 16-lane group per node; per-relation f32 VGPR accs; gathers RAW
//     hb16 rows (12.8 MB, L2-resident); writes Tcat[32][1152] bf16 LDS
//     (+self-loop h slice at k=1024).
//  P2 MFMA: hn = relu(Tcat @ Wcat + bias)   [K=1152]  -> hnb (bf16 swz LDS)
//  P3 MFMA: y  = hn @ ffn_w^T + ffn_b + h   [K=128]   -> aggy (aliases Tcat)
//  P4 LayerNorm -> out
__global__ __launch_bounds__(512)
void k_mega(const bf16* __restrict__ hb16, const uint2* __restrict__ recs,
            const int* __restrict__ base, const bf16* __restrict__ WcatT,
            const float* __restrict__ bias,
            const bf16* __restrict__ fwTb, const float* __restrict__ ffn_b,
            const float* __restrict__ ln_g, const float* __restrict__ ln_b,
            float* __restrict__ out) {
    __shared__ __align__(16) char T_lds[TN * 2304];   // 72 KB bf16, swz 16B-in-256B
    __shared__ __align__(16) char hnb[TN * 256];      // 8 KB bf16 swz
    char* aggy = T_lds;                               // 16 KB alias (phase 3/4)
    const int t = threadIdx.x, wv = t >> 6, l = t & 63;
    const int n0 = blockIdx.x * TN;

    // ---- P1: gather ----
    const int grp = t >> 4;          // 0..31: one node per 16-lane group
    const int c = l & 15;
    const int gbase = l & 48;        // group's base lane within wave
    const int n = n0 + grp;
    float acc[NREL][8] = {};
    if (n < N_NODES) {
        const int b0 = base[n], b1 = base[n + 1];
        for (int eb = b0; eb < b1; eb += 4) {
            const int rem = b1 - eb;
            uint2 md = (c < 4 && c < rem) ? recs[eb + c] : uint2{0u, 0u};
            unsigned sk[4]; float wk[4];
#pragma unroll
            for (int k = 0; k < 4; ++k) {
                sk[k] = (unsigned)__shfl((int)md.x, gbase + k);
                wk[k] = __uint_as_float(__shfl((int)md.y, gbase + k));
            }
            frag_u f0, f1, f2, f3;   // 4 independent L2 loads in flight
            f0.v = *(const bf16x8*)(hb16 + (long long)(sk[0] >> 3) * DIM + c * 8);
            f1.v = *(const bf16x8*)(hb16 + (long long)(sk[1] >> 3) * DIM + c * 8);
            f2.v = *(const bf16x8*)(hb16 + (long long)(sk[2] >> 3) * DIM + c * 8);
            f3.v = *(const bf16x8*)(hb16 + (long long)(sk[3] >> 3) * DIM + c * 8);
#define UPD(R, F, W) { _Pragma("unroll") for (int q = 0; q < 8; ++q) \
    acc[R][q] = fmaf(W, __bfloat162float(F.e[q]), acc[R][q]); }
#define ACCUM(K, F) if (K < rem) { const unsigned r_ = sk[K] & 7u; const float w_ = wk[K]; \
    if      (r_ == 0) UPD(0, F, w_) else if (r_ == 1) UPD(1, F, w_) \
    else if (r_ == 2) UPD(2, F, w_) else if (r_ == 3) UPD(3, F, w_) \
    else if (r_ == 4) UPD(4, F, w_) else if (r_ == 5) UPD(5, F, w_) \
    else if (r_ == 6) UPD(6, F, w_) else               UPD(7, F, w_) }
            ACCUM(0, f0) ACCUM(1, f1) ACCUM(2, f2) ACCUM(3, f3)
#undef ACCUM
#undef UPD
        }
    }
    // write Tcat row (grp): 8 relation slices + self-loop slice
    {
        const int rbase = grp * 2304;
        const int x = (grp & 15) << 4;
#pragma unroll
        for (int r = 0; r < NREL; ++r) {
            frag_u o;
#pragma unroll
            for (int q = 0; q < 8; ++q) o.e[q] = __float2bfloat16(acc[r][q]);
            *(bf16x8*)(T_lds + rbase + ((r * 256 + c * 16) ^ x)) = o.v;
        }
        const long long nc = (n < N_NODES) ? n : (N_NODES - 1);
        frag_u sf;
        sf.v = *(const bf16x8*)(hb16 + nc * DIM + c * 8);
        *(bf16x8*)(T_lds + rbase + ((2048 + c * 16) ^ x)) = sf.v;
    }
    __syncthreads();

    // ---- P2: hn = relu(Tcat @ Wcat + bias), K = 1152 ----
    const int lrow = l & 15, kgrp = l >> 4;
    const int arow = (wv & 1) * 16 + lrow;          // 0..31
    const int cw = (wv >> 1) * 32;                  // col block (32 wide)
    {
        f32x4 acc1[2];
#pragma unroll
        for (int nt = 0; nt < 2; ++nt) acc1[nt] = f32x4{0.f, 0.f, 0.f, 0.f};
        const int ax = (arow & 15) << 4;
        const int abase = arow * 2304;
#pragma unroll 4
        for (int ks = 0; ks < KCAT / 32; ++ks) {
            frag_u a;
            a.v = *(const bf16x8*)(T_lds + abase + ((ks * 64 + kgrp * 16) ^ ax));
#pragma unroll
            for (int nt = 0; nt < 2; ++nt) {
                frag_u b;
                b.v = *(const bf16x8*)(WcatT + (long long)(cw + nt * 16 + lrow) * KCAT +
                                       ks * 32 + kgrp * 8);
                acc1[nt] = __builtin_amdgcn_mfma_f32_16x16x32_bf16(
                    b.v, a.v, acc1[nt], 0, 0, 0);
            }
        }
        const int xb = swzb(arow);
#pragma unroll
        for (int nt = 0; nt < 2; ++nt) {
            int col = cw + nt * 16 + kgrp * 4;
            f32x4 bi = *(const f32x4*)(bias + col);
            pack4_u p;
#pragma unroll
            for (int j = 0; j < 4; ++j)
                p.b[j] = __float2bfloat16(fmaxf(acc1[nt][j] + bi[j], 0.f));
            *(unsigned long long*)(hnb + ((arow * 256 + col * 2) ^ xb)) = p.ll;
        }
    }
    __syncthreads();

    // ---- P3: y = hn @ ffn_w^T + ffn_b + h, K = 128 -> aggy (aliases Tcat) ----
    {
        f32x4 acc2[2];
#pragma unroll
        for (int nt = 0; nt < 2; ++nt) acc2[nt] = f32x4{0.f, 0.f, 0.f, 0.f};
        const int xb = swzb(arow);
#pragma unroll
        for (int ks = 0; ks < 4; ++ks) {
            frag_u a;
            a.v = *(const bf16x8*)(hnb + ((arow * 256 + ks * 64 + kgrp * 16) ^ xb));
#pragma unroll
            for (int nt = 0; nt < 2; ++nt) {
                frag_u b;
                b.v = *(const bf16x8*)(fwTb + (cw + nt * 16 + lrow) * DIM +
                                       ks * 32 + kgrp * 8);
                acc2[nt] = __builtin_amdgcn_mfma_f32_16x16x32_bf16(
                    b.v, a.v, acc2[nt], 0, 0, 0);
            }
        }
        const int grow = n0 + arow;
        const long long growc = (grow < N_NODES) ? grow : (N_NODES - 1);
        const int xy = swzy(arow);
#pragma unroll
        for (int nt = 0; nt < 2; ++nt) {
            int col = cw + nt * 16 + kgrp * 4;
            f32x4 fb = *(const f32x4*)(ffn_b + col);
            pack4_u hp;
            hp.ll = *(const unsigned long long*)(hb16 + growc * DIM + col);
            f32x4 y;
#pragma unroll
            for (int j = 0; j < 4; ++j)
                y[j] = acc2[nt][j] + fb[j] + __bfloat162float(hp.b[j]);
            *(f32x4*)(aggy + arow * 512 + ((col * 4) ^ xy)) = y;
        }
    }
    __syncthreads();

    // ---- P4: LayerNorm. 8 waves x 4 rows. Addr swizzled, col = PRE-swz 2l. ----
#pragma unroll 1
    for (int jr = 0; jr < 4; ++jr) {
        const int row = wv * 4 + jr;
        const int nn = n0 + row;
        const int x = swzy(row);
        float2 yv = *(const float2*)(aggy + row * 512 + ((l * 8) ^ x));
        const int col = l * 2;
        float s = yv.x + yv.y, s2 = yv.x * yv.x + yv.y * yv.y;
#pragma unroll
        for (int m = 1; m < 64; m <<= 1) {
            s  += __shfl_xor(s, m);
            s2 += __shfl_xor(s2, m);
        }
        if (nn < N_NODES) {
            float mu  = s * (1.f / DIM);
            float var = s2 * (1.f / DIM) - mu * mu;
            float inv = rsqrtf(var + 1e-8f);
            float2 gv = *(const float2*)(ln_g + col);
            float2 bv = *(const float2*)(ln_b + col);
            float2 o2{(yv.x - mu) * inv * gv.x + bv.x,
                      (yv.y - mu) * inv * gv.y + bv.y};
            *(float2*)(out + (long long)nn * DIM + col) = o2;
        }
    }
}

// ---------------------------------------------------------------------------
extern "C" void kernel_launch(void* const* d_in, const int* in_sizes, int n_in,
                              void* d_out, int out_size, void* d_ws, size_t ws_size,
                              hipStream_t stream) {
    const float* h      = (const float*)d_in[0];
    const float* V      = (const float*)d_in[1];
    const float* w_comp = (const float*)d_in[2];
    const float* loop_w = (const float*)d_in[3];
    const float* bias   = (const float*)d_in[4];
    const float* ffn_w  = (const float*)d_in[5];
    const float* ffn_b  = (const float*)d_in[6];
    const float* ln_g   = (const float*)d_in[7];
    const float* ln_b   = (const float*)d_in[8];
    const float* norm   = (const float*)d_in[9];
    const int*   src    = (const int*)d_in[10];
    const int*   dst    = (const int*)d_in[11];
    const int*   etype  = (const int*)d_in[12];
    float* out = (float*)d_out;

    if (ws_size < (size_t)WS_NEEDED) return;

    char* ws = (char*)d_ws;
    bf16*  hb16  = (bf16*)(ws + HB16_OFF);
    uint2* recs  = (uint2*)(ws + RECS_OFF);
    int*   base  = (int*)(ws + BASE_OFF);
    int*   cur   = (int*)(ws + CUR_OFF);
    bf16*  WcatT = (bf16*)(ws + WCAT_OFF);
    bf16*  fwTb  = (bf16*)(ws + FWT_OFF);

    hipMemsetAsync(cur, 0, N_NODES * sizeof(int), stream);

    k_prep<<<dim3(3125), dim3(256), 0, stream>>>(
        h, V, w_comp, loop_w, ffn_w, dst, hb16, WcatT, fwTb, cur);

    k_scan<<<dim3(1), dim3(1024), 0, stream>>>(cur, base);
    k_scatter<<<dim3((N_EDGES + 255) / 256), dim3(256), 0, stream>>>(
        src, dst, etype, norm, cur, recs);

    k_mega<<<dim3((N_NODES + TN - 1) / TN), dim3(512), 0, stream>>>(
        hb16, recs, base, WcatT, bias, fwTb, ffn_b, ln_g, ln_b, out);
}